// Round 6
// baseline (370.813 us; speedup 1.0000x reference)
//
#include <hip/hip_runtime.h>

// BarlowTwinsDiversityLoss: N=100000 nodes, K=8 heads, D=128.
// loss = mean_n [ sum_{k,l} (cc_nkl - delta_kl)^2 ],  cc = normalized Gram.
// Memory-bound (409.6 MB read once; ~0.9 GFLOP).
// Round-6: EXACT round-4 main body (84 VGPR, 88.7 us — proven) with ONE
// change: second kernel replaced by per-block fp64 atomicAdd + last-block
// finalize. Lessons encoded:
//  - r3: never cap VGPRs (__launch_bounds__(.,4) -> 39 MB scratch spill).
//  - r5: big fused-reduce tails / lambda pipelines perturb the register
//    allocator (it chose 64 VGPR and serialized loads -> 176 us). Keep the
//    tail tiny: one atomicAdd(double) + counter on lane 0 only.

#define EPS 1e-8f

constexpr int D = 128;
constexpr int BLOCK = 64;             // 1 wave
constexpr int NODES_PER_BLOCK = 16;   // 16 nodes/wave, 4 lanes/node

__global__ __launch_bounds__(BLOCK) void btd_main(
    const float* __restrict__ h0, const float* __restrict__ h1,
    const float* __restrict__ h2, const float* __restrict__ h3,
    const float* __restrict__ h4, const float* __restrict__ h5,
    const float* __restrict__ h6, const float* __restrict__ h7,
    double* __restrict__ accum, unsigned* __restrict__ counter,
    float* __restrict__ out, int n_nodes, int nblocks)
{
    const int lane = threadIdx.x & 63;
    const int g    = lane >> 2;   // node within wave (0..15)
    const int l    = lane & 3;    // d-slice within node (0..3)
    const int node = blockIdx.x * NODES_PER_BLOCK + g;

    // upper triangle incl. diagonal: idx(k,m) = k*(17-k)/2 + (m-k), k<=m
    float acc[36];
    #pragma unroll
    for (int i = 0; i < 36; ++i) acc[i] = 0.f;

    // 32-bit element offset: max = 100000*128 < 2^24, fits easily.
    const unsigned base = (unsigned)node * D + l * 4;
    #pragma unroll
    for (int i = 0; i < 8; ++i) {
        const unsigned off = base + i * 16;
        float4 v[8];
        v[0] = *reinterpret_cast<const float4*>(h0 + off);
        v[1] = *reinterpret_cast<const float4*>(h1 + off);
        v[2] = *reinterpret_cast<const float4*>(h2 + off);
        v[3] = *reinterpret_cast<const float4*>(h3 + off);
        v[4] = *reinterpret_cast<const float4*>(h4 + off);
        v[5] = *reinterpret_cast<const float4*>(h5 + off);
        v[6] = *reinterpret_cast<const float4*>(h6 + off);
        v[7] = *reinterpret_cast<const float4*>(h7 + off);
        int idx = 0;
        #pragma unroll
        for (int k = 0; k < 8; ++k) {
            #pragma unroll
            for (int m = k; m < 8; ++m) {
                acc[idx] += v[k].x * v[m].x + v[k].y * v[m].y
                          + v[k].z * v[m].z + v[k].w * v[m].w;
                ++idx;
            }
        }
    }

    // butterfly sum across the 4 lanes of this node's group
    #pragma unroll
    for (int i = 0; i < 36; ++i) {
        acc[i] += __shfl_xor(acc[i], 1, 64);
        acc[i] += __shfl_xor(acc[i], 2, 64);
    }

    // all 4 lanes compute the node loss redundantly (no divergence), scale 0.25
    float inv[8];
    float loss = 0.f;
    #pragma unroll
    for (int k = 0; k < 8; ++k) {
        const int dk = k * (17 - k) / 2;
        inv[k] = rsqrtf(fmaxf(acc[dk], EPS * EPS));
        const float dterm = acc[dk] * inv[k] * inv[k] - 1.0f;  // cc_kk - 1
        loss += dterm * dterm;
    }
    #pragma unroll
    for (int k = 0; k < 8; ++k) {
        #pragma unroll
        for (int m = k + 1; m < 8; ++m) {
            const float cc = acc[k * (17 - k) / 2 + (m - k)] * inv[k] * inv[m];
            loss += 2.0f * cc * cc;   // (k,l) and (l,k)
        }
    }
    loss *= 0.25f;

    // wave reduction; lane 0 accumulates globally
    #pragma unroll
    for (int off = 32; off > 0; off >>= 1)
        loss += __shfl_down(loss, off, 64);

    if (lane == 0) {
        atomicAdd(accum, (double)loss);        // device-scope RMW
        __threadfence();                       // release before counter bump
        const unsigned old = atomicAdd(counter, 1u);
        if (old == (unsigned)(nblocks - 1)) {
            __threadfence();                   // acquire all blocks' adds
            const double s = atomicAdd(accum, 0.0);  // coherent RMW read
            out[0] = (float)(s / (double)n_nodes);
        }
    }
}

extern "C" void kernel_launch(void* const* d_in, const int* in_sizes, int n_in,
                              void* d_out, int out_size, void* d_ws, size_t ws_size,
                              hipStream_t stream) {
    const int n_nodes = in_sizes[0] / D;   // 100000
    const int nblocks = (n_nodes + NODES_PER_BLOCK - 1) / NODES_PER_BLOCK;  // 6250

    // ws layout: [0..7] double accumulator, [8..11] arrival counter
    hipMemsetAsync(d_ws, 0, 16, stream);

    btd_main<<<nblocks, BLOCK, 0, stream>>>(
        (const float*)d_in[0], (const float*)d_in[1],
        (const float*)d_in[2], (const float*)d_in[3],
        (const float*)d_in[4], (const float*)d_in[5],
        (const float*)d_in[6], (const float*)d_in[7],
        (double*)d_ws, (unsigned*)((char*)d_ws + 8),
        (float*)d_out, n_nodes, nblocks);
}

// Round 7
// 84.086 us; speedup vs baseline: 4.4099x; 4.4099x over previous
//
#include <hip/hip_runtime.h>

// BarlowTwinsDiversityLoss: N=100000 nodes, K=8 heads, D=128.
// loss = mean_n [ sum_{k,l} (cc_nkl - delta_kl)^2 ],  cc = normalized Gram.
// Memory-bound (409.6 MB read once; ~0.9 GFLOP).
// Round-7: EXACT round-4 main kernel (proven 88.7 us, 84 VGPR, no spill).
// Only change: btd_reduce uses 1024 threads (serial loop 25 -> 7 iters).
// Lessons encoded:
//  - r3: never cap VGPRs (__launch_bounds__(.,4) -> 39 MB scratch spill).
//  - r5: fused-reduce tails perturb regalloc (64 VGPR -> serialized loads).
//  - r6: single-address device atomics serialize (6250 RMW -> +280 us).
//  Two-kernel deterministic reduction is the stable optimum.

#define EPS 1e-8f

constexpr int D = 128;
constexpr int BLOCK = 64;             // 1 wave
constexpr int NODES_PER_BLOCK = 16;   // 16 nodes/wave, 4 lanes/node

__global__ __launch_bounds__(BLOCK) void btd_main(
    const float* __restrict__ h0, const float* __restrict__ h1,
    const float* __restrict__ h2, const float* __restrict__ h3,
    const float* __restrict__ h4, const float* __restrict__ h5,
    const float* __restrict__ h6, const float* __restrict__ h7,
    float* __restrict__ partials, int n_nodes)
{
    const int lane = threadIdx.x & 63;
    const int g    = lane >> 2;   // node within wave (0..15)
    const int l    = lane & 3;    // d-slice within node (0..3)
    const int node = blockIdx.x * NODES_PER_BLOCK + g;

    // upper triangle incl. diagonal: idx(k,m) = k*(17-k)/2 + (m-k), k<=m
    float acc[36];
    #pragma unroll
    for (int i = 0; i < 36; ++i) acc[i] = 0.f;

    // 32-bit element offset: max = 100000*128 < 2^24, fits easily.
    const unsigned base = (unsigned)node * D + l * 4;
    #pragma unroll
    for (int i = 0; i < 8; ++i) {
        const unsigned off = base + i * 16;
        float4 v[8];
        v[0] = *reinterpret_cast<const float4*>(h0 + off);
        v[1] = *reinterpret_cast<const float4*>(h1 + off);
        v[2] = *reinterpret_cast<const float4*>(h2 + off);
        v[3] = *reinterpret_cast<const float4*>(h3 + off);
        v[4] = *reinterpret_cast<const float4*>(h4 + off);
        v[5] = *reinterpret_cast<const float4*>(h5 + off);
        v[6] = *reinterpret_cast<const float4*>(h6 + off);
        v[7] = *reinterpret_cast<const float4*>(h7 + off);
        int idx = 0;
        #pragma unroll
        for (int k = 0; k < 8; ++k) {
            #pragma unroll
            for (int m = k; m < 8; ++m) {
                acc[idx] += v[k].x * v[m].x + v[k].y * v[m].y
                          + v[k].z * v[m].z + v[k].w * v[m].w;
                ++idx;
            }
        }
    }

    // butterfly sum across the 4 lanes of this node's group
    #pragma unroll
    for (int i = 0; i < 36; ++i) {
        acc[i] += __shfl_xor(acc[i], 1, 64);
        acc[i] += __shfl_xor(acc[i], 2, 64);
    }

    // all 4 lanes compute the node loss redundantly (no divergence), scale 0.25
    float inv[8];
    float loss = 0.f;
    #pragma unroll
    for (int k = 0; k < 8; ++k) {
        const int dk = k * (17 - k) / 2;
        inv[k] = rsqrtf(fmaxf(acc[dk], EPS * EPS));
        const float dterm = acc[dk] * inv[k] * inv[k] - 1.0f;  // cc_kk - 1
        loss += dterm * dterm;
    }
    #pragma unroll
    for (int k = 0; k < 8; ++k) {
        #pragma unroll
        for (int m = k + 1; m < 8; ++m) {
            const float cc = acc[k * (17 - k) / 2 + (m - k)] * inv[k] * inv[m];
            loss += 2.0f * cc * cc;   // (k,l) and (l,k)
        }
    }
    loss *= 0.25f;

    // wave reduction; lane 0 writes the block partial
    #pragma unroll
    for (int off = 32; off > 0; off >>= 1)
        loss += __shfl_down(loss, off, 64);
    if (lane == 0) partials[blockIdx.x] = loss;
}

__global__ __launch_bounds__(1024) void btd_reduce(
    const float* __restrict__ partials, int nparts,
    float* __restrict__ out, float inv_n)
{
    float s = 0.f;
    for (int i = threadIdx.x; i < nparts; i += 1024) s += partials[i];
    #pragma unroll
    for (int off = 32; off > 0; off >>= 1) s += __shfl_down(s, off, 64);
    __shared__ float smem[16];
    const int lane = threadIdx.x & 63, wave = threadIdx.x >> 6;
    if (lane == 0) smem[wave] = s;
    __syncthreads();
    if (threadIdx.x == 0) {
        float t = 0.f;
        #pragma unroll
        for (int w = 0; w < 16; ++w) t += smem[w];
        out[0] = t * inv_n;
    }
}

extern "C" void kernel_launch(void* const* d_in, const int* in_sizes, int n_in,
                              void* d_out, int out_size, void* d_ws, size_t ws_size,
                              hipStream_t stream) {
    const int n_nodes = in_sizes[0] / D;   // 100000
    const int nblocks = (n_nodes + NODES_PER_BLOCK - 1) / NODES_PER_BLOCK;  // 6250
    float* partials = (float*)d_ws;

    btd_main<<<nblocks, BLOCK, 0, stream>>>(
        (const float*)d_in[0], (const float*)d_in[1],
        (const float*)d_in[2], (const float*)d_in[3],
        (const float*)d_in[4], (const float*)d_in[5],
        (const float*)d_in[6], (const float*)d_in[7],
        partials, n_nodes);

    btd_reduce<<<1, 1024, 0, stream>>>(partials, nblocks,
                                       (float*)d_out, 1.0f / (float)n_nodes);
}

// Round 9
// 83.730 us; speedup vs baseline: 4.4287x; 1.0043x over previous
//
#include <hip/hip_runtime.h>

// BarlowTwinsDiversityLoss: N=100000 nodes, K=8 heads, D=128.
// loss = mean_n [ sum_{k,l} (cc_nkl - delta_kl)^2 ],  cc = normalized Gram.
// Memory-bound (409.6 MB read once per call; 256 MiB L3).
// Round-9: round-8 retry with the compile fix — __builtin_nontemporal_load
// requires a native clang vector type, not HIP_vector_type<float,4>.
// h5,h6,h7 loads are non-temporal (no-allocate) so heads h0-h4
// (5*51.2 = 256.0 MB) stay L3-resident across graph replays.
// Lessons encoded: r3 no VGPR caps; r5 no fused tails; r6 no same-line atomics.

#define EPS 1e-8f

constexpr int D = 128;
constexpr int BLOCK = 64;             // 1 wave
constexpr int NODES_PER_BLOCK = 16;   // 16 nodes/wave, 4 lanes/node

typedef float vfloat4 __attribute__((ext_vector_type(4)));  // native vector

__global__ __launch_bounds__(BLOCK) void btd_main(
    const float* __restrict__ h0, const float* __restrict__ h1,
    const float* __restrict__ h2, const float* __restrict__ h3,
    const float* __restrict__ h4, const float* __restrict__ h5,
    const float* __restrict__ h6, const float* __restrict__ h7,
    float* __restrict__ partials, int n_nodes)
{
    const int lane = threadIdx.x & 63;
    const int g    = lane >> 2;   // node within wave (0..15)
    const int l    = lane & 3;    // d-slice within node (0..3)
    const int node = blockIdx.x * NODES_PER_BLOCK + g;

    // upper triangle incl. diagonal: idx(k,m) = k*(17-k)/2 + (m-k), k<=m
    float acc[36];
    #pragma unroll
    for (int i = 0; i < 36; ++i) acc[i] = 0.f;

    const unsigned base = (unsigned)node * D + l * 4;
    #pragma unroll
    for (int i = 0; i < 8; ++i) {
        const unsigned off = base + i * 16;
        vfloat4 v[8];
        v[0] = *reinterpret_cast<const vfloat4*>(h0 + off);
        v[1] = *reinterpret_cast<const vfloat4*>(h1 + off);
        v[2] = *reinterpret_cast<const vfloat4*>(h2 + off);
        v[3] = *reinterpret_cast<const vfloat4*>(h3 + off);
        v[4] = *reinterpret_cast<const vfloat4*>(h4 + off);
        // non-temporal: don't displace h0-h4 from L3 (exactly 256 MB resident)
        v[5] = __builtin_nontemporal_load(reinterpret_cast<const vfloat4*>(h5 + off));
        v[6] = __builtin_nontemporal_load(reinterpret_cast<const vfloat4*>(h6 + off));
        v[7] = __builtin_nontemporal_load(reinterpret_cast<const vfloat4*>(h7 + off));
        int idx = 0;
        #pragma unroll
        for (int k = 0; k < 8; ++k) {
            #pragma unroll
            for (int m = k; m < 8; ++m) {
                acc[idx] += v[k].x * v[m].x + v[k].y * v[m].y
                          + v[k].z * v[m].z + v[k].w * v[m].w;
                ++idx;
            }
        }
    }

    // butterfly sum across the 4 lanes of this node's group
    #pragma unroll
    for (int i = 0; i < 36; ++i) {
        acc[i] += __shfl_xor(acc[i], 1, 64);
        acc[i] += __shfl_xor(acc[i], 2, 64);
    }

    // all 4 lanes compute the node loss redundantly (no divergence), scale 0.25
    float inv[8];
    float loss = 0.f;
    #pragma unroll
    for (int k = 0; k < 8; ++k) {
        const int dk = k * (17 - k) / 2;
        inv[k] = rsqrtf(fmaxf(acc[dk], EPS * EPS));
        const float dterm = acc[dk] * inv[k] * inv[k] - 1.0f;  // cc_kk - 1
        loss += dterm * dterm;
    }
    #pragma unroll
    for (int k = 0; k < 8; ++k) {
        #pragma unroll
        for (int m = k + 1; m < 8; ++m) {
            const float cc = acc[k * (17 - k) / 2 + (m - k)] * inv[k] * inv[m];
            loss += 2.0f * cc * cc;   // (k,l) and (l,k)
        }
    }
    loss *= 0.25f;

    // wave reduction; lane 0 writes the block partial
    #pragma unroll
    for (int off = 32; off > 0; off >>= 1)
        loss += __shfl_down(loss, off, 64);
    if (lane == 0) partials[blockIdx.x] = loss;
}

__global__ __launch_bounds__(1024) void btd_reduce(
    const float* __restrict__ partials, int nparts,
    float* __restrict__ out, float inv_n)
{
    float s = 0.f;
    for (int i = threadIdx.x; i < nparts; i += 1024) s += partials[i];
    #pragma unroll
    for (int off = 32; off > 0; off >>= 1) s += __shfl_down(s, off, 64);
    __shared__ float smem[16];
    const int lane = threadIdx.x & 63, wave = threadIdx.x >> 6;
    if (lane == 0) smem[wave] = s;
    __syncthreads();
    if (threadIdx.x == 0) {
        float t = 0.f;
        #pragma unroll
        for (int w = 0; w < 16; ++w) t += smem[w];
        out[0] = t * inv_n;
    }
}

extern "C" void kernel_launch(void* const* d_in, const int* in_sizes, int n_in,
                              void* d_out, int out_size, void* d_ws, size_t ws_size,
                              hipStream_t stream) {
    const int n_nodes = in_sizes[0] / D;   // 100000
    const int nblocks = (n_nodes + NODES_PER_BLOCK - 1) / NODES_PER_BLOCK;  // 6250
    float* partials = (float*)d_ws;

    btd_main<<<nblocks, BLOCK, 0, stream>>>(
        (const float*)d_in[0], (const float*)d_in[1],
        (const float*)d_in[2], (const float*)d_in[3],
        (const float*)d_in[4], (const float*)d_in[5],
        (const float*)d_in[6], (const float*)d_in[7],
        partials, n_nodes);

    btd_reduce<<<1, 1024, 0, stream>>>(partials, nblocks,
                                       (float*)d_out, 1.0f / (float)n_nodes);
}